// Round 10
// baseline (247.031 us; speedup 1.0000x reference)
//
#include <hip/hip_runtime.h>
#include <hip/hip_fp16.h>

// TV Chambolle, image (8, 2048, 128) f32: 29 p-updates + final out = x + div(p) + bias.
// v = b*SB + t*ST + f.
//
// R22 = R21 (R13 fp32 cone kernels + packed-P fused tail; 245.4us) minus one
// provably redundant barrier in k_tail:
//  - the sync before publish_t(4) protected nothing: publish(4)'s p1if/p2b
//    writes vs phase_out(3)'s reads are ordered by iter-3's sync2; upd(3)'s
//    outx reads vs phase_out(4)'s writes are ordered by the sync AFTER
//    publish(4). Removed.
// Session model (R13-R21, measured): total ~= 7 launches x (7us fixed + ~9us
// VALU/trans + ~5us mem + ~4us barrier+stall) at toolchain-capped 2 waves/SIMD.
// Levers measured null: occupancy (6 configs; VGPR caps pinned), coop persistent
// kernel (3.7x worse), HH != 4, extra packing (cvt tax), barrier reduction
// (2/iter forced by cross-wave LDS exchange). One real win: DPP b-shifts (-9us).

#define BB 8
#define TT 2048
#define FF 128
#define NV (BB*TT*FF)        // 2,097,152
#define SB (TT*FF)           // 262144
#define ST FF                // 128
#define RR 8                 // owned t-rows per block
#define NBLK (TT/RR)         // 256
#define HH 4                 // cone iterations per launch
#define EE 16                // extended rows (k_first / k_mid)
#define GR 8                 // rows per row-group (k_first / k_mid)
#define EET 18               // extended rows (k_tail)
#define GRT 9                // rows per row-group (k_tail)
#define HLT 5                // tail halo below owned

constexpr float TAU = 1.0f / 6.0f;

__device__ __forceinline__ float4 ld4(const float* p) { return *reinterpret_cast<const float4*>(p); }
__device__ __forceinline__ void st4(float* p, const float4& v) { *reinterpret_cast<float4*>(p) = v; }
// packed fp16 <-> fp32x4 (8-byte transactions)
__device__ __forceinline__ float4 ld4h(const __half* p) {
    uint2 u = *reinterpret_cast<const uint2*>(p);
    __half2 h0 = *reinterpret_cast<__half2*>(&u.x);
    __half2 h1 = *reinterpret_cast<__half2*>(&u.y);
    float2 a = __half22float2(h0), b2 = __half22float2(h1);
    return make_float4(a.x, a.y, b2.x, b2.y);
}
__device__ __forceinline__ void st4h(__half* p, const float4& v) {
    __half2 h0 = __float22half2_rn(make_float2(v.x, v.y));
    __half2 h1 = __float22half2_rn(make_float2(v.z, v.w));
    uint2 u;
    u.x = *reinterpret_cast<unsigned*>(&h0);
    u.y = *reinterpret_cast<unsigned*>(&h1);
    *reinterpret_cast<uint2*>(p) = u;
}
// packed 4 x fp16 in registers (2 VGPRs) -- tail only
struct h4 { __half2 lo, hi; };
__device__ __forceinline__ float4 h2f(const h4& h) {
    float2 a = __half22float2(h.lo), b = __half22float2(h.hi);
    return make_float4(a.x, a.y, b.x, b.y);
}
__device__ __forceinline__ h4 f2h(const float4& v) {
    h4 r;
    r.lo = __float22half2_rn(make_float2(v.x, v.y));
    r.hi = __float22half2_rn(make_float2(v.z, v.w));
    return r;
}
__device__ __forceinline__ h4 h4z() {
    h4 r; unsigned z = 0;
    r.lo = *reinterpret_cast<__half2*>(&z);
    r.hi = *reinterpret_cast<__half2*>(&z);
    return r;
}
__device__ __forceinline__ h4 ld4hp(const __half* p) {   // raw 8B, no cvt
    uint2 u = *reinterpret_cast<const uint2*>(p);
    h4 r;
    r.lo = *reinterpret_cast<__half2*>(&u.x);
    r.hi = *reinterpret_cast<__half2*>(&u.y);
    return r;
}

// DPP lane shifts (VALU, no DS pipe). row_shr:1 = src[n-1] (shfl_up 1);
// row_shl:1 = src[n+1] (shfl_down 1). 16-lane-row boundary lanes -> 0
// (bound_ctrl=1); all consumers masked by b>0 / b<BB-1 which covers them.
__device__ __forceinline__ float dpp_shr1(float v) {
    return __int_as_float(__builtin_amdgcn_update_dpp(
        0, __float_as_int(v), 0x111, 0xF, 0xF, true));
}
__device__ __forceinline__ float dpp_shl1(float v) {
    return __int_as_float(__builtin_amdgcn_update_dpp(
        0, __float_as_int(v), 0x101, 0xF, 0xF, true));
}
__device__ __forceinline__ float4 dpp_up4(const float4& v) {
    return make_float4(dpp_shr1(v.x), dpp_shr1(v.y), dpp_shr1(v.z), dpp_shr1(v.w));
}
__device__ __forceinline__ float4 dpp_dn4(const float4& v) {
    return make_float4(dpp_shl1(v.x), dpp_shl1(v.y), dpp_shl1(v.z), dpp_shl1(v.w));
}
__device__ __forceinline__ h4 dpp_up_h4(const h4& v) {   // packed: 2 DPP ops
    unsigned lo = *reinterpret_cast<const unsigned*>(&v.lo);
    unsigned hi = *reinterpret_cast<const unsigned*>(&v.hi);
    unsigned rl = (unsigned)__builtin_amdgcn_update_dpp(0, (int)lo, 0x111, 0xF, 0xF, true);
    unsigned rh = (unsigned)__builtin_amdgcn_update_dpp(0, (int)hi, 0x111, 0xF, 0xF, true);
    h4 r;
    r.lo = *reinterpret_cast<__half2*>(&rl);
    r.hi = *reinterpret_cast<__half2*>(&rh);
    return r;
}
__device__ __forceinline__ float4 sub4(const float4& a, const float4& b) {
    return make_float4(a.x - b.x, a.y - b.y, a.z - b.z, a.w - b.w);
}
__device__ __forceinline__ float4 f4z() { return make_float4(0.f, 0.f, 0.f, 0.f); }
// 1/(|g|*s + 1) elementwise; v_sqrt_f32 + v_rcp_f32 approx.
__device__ __forceinline__ float4 nbvec(const float4& gB, const float4& gT, const float4& gF, float s) {
    float4 nb; float q;
    q = gB.x * gB.x + gT.x * gT.x + gF.x * gF.x;
    nb.x = __builtin_amdgcn_rcpf(fmaf(__builtin_amdgcn_sqrtf(q), s, 1.f));
    q = gB.y * gB.y + gT.y * gT.y + gF.y * gF.y;
    nb.y = __builtin_amdgcn_rcpf(fmaf(__builtin_amdgcn_sqrtf(q), s, 1.f));
    q = gB.z * gB.z + gT.z * gT.z + gF.z * gF.z;
    nb.z = __builtin_amdgcn_rcpf(fmaf(__builtin_amdgcn_sqrtf(q), s, 1.f));
    q = gB.w * gB.w + gT.w * gT.w + gF.w * gF.w;
    nb.w = __builtin_amdgcn_rcpf(fmaf(__builtin_amdgcn_sqrtf(q), s, 1.f));
    return nb;
}

// ==================================================================
// ============== fp32 cone (k_first / k_mid) -- R13 =================
// ==================================================================
struct ConeShared {                      // ~10 KB
    float p2b[EE][4][8];
    float outx[EE][4][8];
    float4 p1if[256];
    float4 oif[256];
};

template<int RG>
__device__ __forceinline__ void publish(int k, float4 (&P1)[GR], float4 (&P2)[GR],
                                        ConeShared& sh, int c, int b, int fg, int w) {
    if (fg == 7) {
        #pragma unroll
        for (int le = 0; le < GR; ++le) {
            const int e = RG * GR + le;
            if (e >= k && e < EE - k) sh.p2b[e][w][b] = P2[le].w;
        }
    }
    if (RG == 0) sh.p1if[c] = P1[GR - 1];
}

template<int RG, bool ELO, bool EHI>
__device__ __forceinline__ void phase_out(
    int k, const float4 (&Xr)[GR],
    float4 (&P0)[GR], float4 (&P1)[GR], float4 (&P2)[GR], float4 (&O)[GR],
    ConeShared& sh, int c, int b, int fg, int w, int f0, int tb) {
    #pragma unroll
    for (int le = 0; le < GR; ++le) {
        const int e = RG * GR + le;
        if (e < k + 1 || e >= EE - k) continue;
        const int t = tb + e;
        if ((ELO && t < 0) || (EHI && t >= TT)) continue;
        const float4 X = Xr[le];
        float4 o;
        o.x = X.x - P0[le].x - P1[le].x - P2[le].x;
        o.y = X.y - P0[le].y - P1[le].y - P2[le].y + P2[le].x;
        o.z = X.z - P0[le].z - P1[le].z - P2[le].z + P2[le].y;
        o.w = X.w - P0[le].w - P1[le].w - P2[le].w + P2[le].z;
        float4 h0 = dpp_up4(P0[le]);
        if (b > 0) { o.x += h0.x; o.y += h0.y; o.z += h0.z; o.w += h0.w; }
        float4 pm1 = (le > 0) ? P1[le - 1] : sh.p1if[c];
        if (!ELO || t > 0) { o.x += pm1.x; o.y += pm1.y; o.z += pm1.z; o.w += pm1.w; }
        float pw = __shfl_up(P2[le].w, 8);
        if (fg == 0) pw = (w > 0) ? sh.p2b[e][(w - 1)][b] : 0.0f;
        if (f0 > 0) o.x += pw;
        O[le] = o;
        if (fg == 0) sh.outx[e][w][b] = o.x;
    }
}

template<int RG, bool ELO, bool EHI>
__device__ __forceinline__ void phase_upd(
    int k, float4 (&P0)[GR], float4 (&P1)[GR], float4 (&P2)[GR], float4 (&O)[GR],
    ConeShared& sh, int c, int b, int fg, int w, int f0, int tb, float s) {
    #pragma unroll
    for (int le = 0; le < GR; ++le) {
        const int e = RG * GR + le;
        if (e < k + 1 || e > EE - 2 - k) continue;
        const int t = tb + e;
        if ((ELO && t < 0) || (EHI && t >= TT)) continue;
        const float4 cc = O[le];
        const float4 on = (le < GR - 1) ? O[le + 1] : sh.oif[c];
        float4 gT = f4z();
        if (!EHI || t < TT - 1) gT = sub4(on, cc);
        const float4 nB = dpp_dn4(cc);
        float4 gB = f4z();
        if (b < BB - 1) gB = sub4(nB, cc);
        float nxx = __shfl_down(cc.x, 8);
        if (fg == 7) nxx = (w < 3) ? sh.outx[e][w + 1][b] : 0.0f;
        float4 gF;
        gF.x = cc.y - cc.x;
        gF.y = cc.z - cc.y;
        gF.z = cc.w - cc.z;
        gF.w = (f0 < FF - 4) ? (nxx - cc.w) : 0.f;
        const float4 nb = nbvec(gB, gT, gF, s);
        P0[le].x = fmaf(-TAU, gB.x, P0[le].x) * nb.x;
        P0[le].y = fmaf(-TAU, gB.y, P0[le].y) * nb.y;
        P0[le].z = fmaf(-TAU, gB.z, P0[le].z) * nb.z;
        P0[le].w = fmaf(-TAU, gB.w, P0[le].w) * nb.w;
        P1[le].x = fmaf(-TAU, gT.x, P1[le].x) * nb.x;
        P1[le].y = fmaf(-TAU, gT.y, P1[le].y) * nb.y;
        P1[le].z = fmaf(-TAU, gT.z, P1[le].z) * nb.z;
        P1[le].w = fmaf(-TAU, gT.w, P1[le].w) * nb.w;
        P2[le].x = fmaf(-TAU, gF.x, P2[le].x) * nb.x;
        P2[le].y = fmaf(-TAU, gF.y, P2[le].y) * nb.y;
        P2[le].z = fmaf(-TAU, gF.z, P2[le].z) * nb.z;
        P2[le].w = fmaf(-TAU, gF.w, P2[le].w) * nb.w;
    }
}

template<bool ELO, bool EHI>
__device__ __forceinline__ void cone_run(
    const float4 (&Xr)[GR],
    float4 (&P0)[GR], float4 (&P1)[GR], float4 (&P2)[GR], float4 (&O)[GR],
    ConeShared& sh, int rg, int c, int b, int fg, int w, int f0, int tb, float s) {
    #pragma unroll
    for (int k = 0; k < HH; ++k) {
        if (rg == 0) publish<0>(k, P1, P2, sh, c, b, fg, w);
        else         publish<1>(k, P1, P2, sh, c, b, fg, w);
        __syncthreads();
        if (rg == 0) phase_out<0, ELO, EHI>(k, Xr, P0, P1, P2, O, sh, c, b, fg, w, f0, tb);
        else         phase_out<1, ELO, EHI>(k, Xr, P0, P1, P2, O, sh, c, b, fg, w, f0, tb);
        if (rg == 1) sh.oif[c] = O[0];
        __syncthreads();
        if (rg == 0) phase_upd<0, ELO, EHI>(k, P0, P1, P2, O, sh, c, b, fg, w, f0, tb, s);
        else         phase_upd<1, ELO, EHI>(k, P0, P1, P2, O, sh, c, b, fg, w, f0, tb, s);
    }
}

template<bool ELO, bool EHI>
__device__ __forceinline__ void mid_main(
    const float* __restrict__ x, const __half* __restrict__ pin, __half* __restrict__ pout,
    ConeShared& sh, int rg, int c, int b, int fg, int w, int f0, int tb, int e0,
    int base, float s) {
    float4 P0[GR], P1[GR], P2[GR], O[GR], Xr[GR];
    #pragma unroll
    for (int le = 0; le < GR; ++le) {
        const int t = tb + e0 + le;
        const bool ok = (!ELO || t >= 0) && (!EHI || t < TT);
        const bool trim = (rg == 0 && le == 0);
        if (ok) {
            const int v = base + t * ST;
            P1[le] = ld4h(pin + NV + v);
            if (!trim) {
                P0[le] = ld4h(pin + v);
                P2[le] = ld4h(pin + 2 * NV + v);
                Xr[le] = ld4(x + v);
            } else { P0[le] = f4z(); P2[le] = f4z(); Xr[le] = f4z(); }
        } else {
            P0[le] = f4z(); P1[le] = f4z(); P2[le] = f4z(); Xr[le] = f4z();
        }
        O[le] = f4z();
    }
    cone_run<ELO, EHI>(Xr, P0, P1, P2, O, sh, rg, c, b, fg, w, f0, tb, s);
    #pragma unroll
    for (int le = 0; le < GR; ++le) {
        const int e = e0 + le;
        if (e >= HH && e < HH + RR) {
            const int v = base + (tb + e) * ST;
            st4h(pout + v, P0[le]);
            st4h(pout + NV + v, P1[le]);
            st4h(pout + 2 * NV + v, P2[le]);
        }
    }
}

__global__ __launch_bounds__(512, 2)
void k_mid(const float* __restrict__ x, const __half* __restrict__ pin,
           __half* __restrict__ pout, const float* __restrict__ lam) {
    __shared__ ConeShared sh;
    const int tid = threadIdx.x;
    const int blk = blockIdx.x;
    const int rg  = tid >> 8;
    const int c   = tid & 255;
    const int b   = tid & 7;
    const int fg  = (tid >> 3) & 7;
    const int w   = (tid >> 6) & 3;
    const int f0  = w * 32 + fg * 4;
    const int tb  = blk * RR - HH;
    const int e0  = rg * GR;
    const int base = b * SB + f0;
    const float s = TAU / lam[0];
    if (blk == 0 || blk == NBLK - 1)
        mid_main<true, true>(x, pin, pout, sh, rg, c, b, fg, w, f0, tb, e0, base, s);
    else
        mid_main<false, false>(x, pin, pout, sh, rg, c, b, fg, w, f0, tb, e0, base, s);
}

template<bool ELO, bool EHI>
__device__ __forceinline__ void first_main(
    const float* __restrict__ x, __half* __restrict__ pout,
    ConeShared& sh, int rg, int c, int b, int fg, int w, int f0, int tb, int e0,
    int base, float s) {
    float4 P0[GR], P1[GR], P2[GR], O[GR], Xr[GR], XHa;
    #pragma unroll
    for (int le = 0; le < GR; ++le) {
        const int t = tb + e0 + le;
        const bool ok = (!ELO || t >= 0) && (!EHI || t < TT);
        Xr[le] = ok ? ld4(x + base + t * ST) : f4z();
        O[le] = f4z();
    }
    {
        const int t = tb + e0 + GR;
        const bool ok = (!ELO || t >= 0) && (t < TT);
        XHa = ok ? ld4(x + base + t * ST) : f4z();
    }
    #pragma unroll
    for (int le = 0; le < GR; ++le) {
        const int t = tb + e0 + le;
        if ((!ELO || t >= 0) && (!EHI || t < TT)) {
            const float4 cc = Xr[le];
            const float4 nxt = (le < GR - 1) ? Xr[le + 1] : XHa;
            float4 gT = f4z();
            if (t < TT - 1) gT = sub4(nxt, cc);
            const float4 nB = dpp_dn4(cc);
            float4 gB = f4z();
            if (b < BB - 1) gB = sub4(nB, cc);
            float4 gF;
            gF.x = cc.y - cc.x;
            gF.y = cc.z - cc.y;
            gF.z = cc.w - cc.z;
            gF.w = (f0 < FF - 4) ? (x[base + t * ST + 4] - cc.w) : 0.f;
            const float4 nb = nbvec(gB, gT, gF, s);
            P0[le] = make_float4(-TAU * gB.x * nb.x, -TAU * gB.y * nb.y,
                                 -TAU * gB.z * nb.z, -TAU * gB.w * nb.w);
            P1[le] = make_float4(-TAU * gT.x * nb.x, -TAU * gT.y * nb.y,
                                 -TAU * gT.z * nb.z, -TAU * gT.w * nb.w);
            P2[le] = make_float4(-TAU * gF.x * nb.x, -TAU * gF.y * nb.y,
                                 -TAU * gF.z * nb.z, -TAU * gF.w * nb.w);
        } else {
            P0[le] = f4z(); P1[le] = f4z(); P2[le] = f4z();
        }
    }
    cone_run<ELO, EHI>(Xr, P0, P1, P2, O, sh, rg, c, b, fg, w, f0, tb, s);
    #pragma unroll
    for (int le = 0; le < GR; ++le) {
        const int e = e0 + le;
        if (e >= HH && e < HH + RR) {
            const int v = base + (tb + e) * ST;
            st4h(pout + v, P0[le]);
            st4h(pout + NV + v, P1[le]);
            st4h(pout + 2 * NV + v, P2[le]);
        }
    }
}

__global__ __launch_bounds__(512, 2)
void k_first(const float* __restrict__ x, __half* __restrict__ pout,
             const float* __restrict__ lam) {
    __shared__ ConeShared sh;
    const int tid = threadIdx.x;
    const int blk = blockIdx.x;
    const int rg  = tid >> 8;
    const int c   = tid & 255;
    const int b   = tid & 7;
    const int fg  = (tid >> 3) & 7;
    const int w   = (tid >> 6) & 3;
    const int f0  = w * 32 + fg * 4;
    const int tb  = blk * RR - HH;
    const int e0  = rg * GR;
    const int base = b * SB + f0;
    const float s = TAU / lam[0];
    if (blk == 0 || blk == NBLK - 1)
        first_main<true, true>(x, pout, sh, rg, c, b, fg, w, f0, tb, e0, base, s);
    else
        first_main<false, false>(x, pout, sh, rg, c, b, fg, w, f0, tb, e0, base, s);
}

// ==================================================================
// ============== packed-P cone tail (EE=18, GR=9) ===================
// ==================================================================
struct ConeSharedT {                     // ~10.8 KB
    float p2b[EET][4][8];
    float outx[EET][4][8];
    h4 p1if[256];
    float4 oif[256];
};

template<int RG>
__device__ __forceinline__ void publish_t(int k, h4 (&P1)[GRT], h4 (&P2)[GRT],
                                          ConeSharedT& sh, int c, int b, int fg, int w) {
    if (fg == 7) {
        #pragma unroll
        for (int le = 0; le < GRT; ++le) {
            const int e = RG * GRT + le;
            if (e >= k && e < EET - k) sh.p2b[e][w][b] = __high2float(P2[le].hi);
        }
    }
    if (RG == 0) sh.p1if[c] = P1[GRT - 1];
}

template<int RG, bool ELO, bool EHI>
__device__ __forceinline__ void phase_out_t(
    int k, const float4 (&Xr)[GRT],
    h4 (&P0)[GRT], h4 (&P1)[GRT], h4 (&P2)[GRT], float4 (&O)[GRT],
    ConeSharedT& sh, int c, int b, int fg, int w, int f0, int tb) {
    #pragma unroll
    for (int le = 0; le < GRT; ++le) {
        const int e = RG * GRT + le;
        if (e < k + 1 || e >= EET - k) continue;
        const int t = tb + e;
        if ((ELO && t < 0) || (EHI && t >= TT)) continue;
        const float4 X = Xr[le];
        const float4 p0 = h2f(P0[le]);
        const float4 p1 = h2f(P1[le]);
        const float4 p2 = h2f(P2[le]);
        float4 o;
        o.x = X.x - p0.x - p1.x - p2.x;
        o.y = X.y - p0.y - p1.y - p2.y + p2.x;
        o.z = X.z - p0.z - p1.z - p2.z + p2.y;
        o.w = X.w - p0.w - p1.w - p2.w + p2.z;
        const float4 h0 = h2f(dpp_up_h4(P0[le]));
        if (b > 0) { o.x += h0.x; o.y += h0.y; o.z += h0.z; o.w += h0.w; }
        const h4 pm1h = (le > 0) ? P1[le - 1] : sh.p1if[c];
        const float4 pm1 = h2f(pm1h);
        if (!ELO || t > 0) { o.x += pm1.x; o.y += pm1.y; o.z += pm1.z; o.w += pm1.w; }
        float pw = __shfl_up(p2.w, 8);
        if (fg == 0) pw = (w > 0) ? sh.p2b[e][(w - 1)][b] : 0.0f;
        if (f0 > 0) o.x += pw;
        O[le] = o;
        if (fg == 0) sh.outx[e][w][b] = o.x;
    }
}

template<int RG, bool ELO, bool EHI>
__device__ __forceinline__ void phase_upd_t(
    int k, h4 (&P0)[GRT], h4 (&P1)[GRT], h4 (&P2)[GRT], float4 (&O)[GRT],
    ConeSharedT& sh, int c, int b, int fg, int w, int f0, int tb, float s) {
    #pragma unroll
    for (int le = 0; le < GRT; ++le) {
        const int e = RG * GRT + le;
        if (e < k + 1 || e > EET - 2 - k) continue;
        const int t = tb + e;
        if ((ELO && t < 0) || (EHI && t >= TT)) continue;
        const float4 cc = O[le];
        const float4 on = (le < GRT - 1) ? O[le + 1] : sh.oif[c];
        float4 gT = f4z();
        if (!EHI || t < TT - 1) gT = sub4(on, cc);
        const float4 nB = dpp_dn4(cc);
        float4 gB = f4z();
        if (b < BB - 1) gB = sub4(nB, cc);
        float nxx = __shfl_down(cc.x, 8);
        if (fg == 7) nxx = (w < 3) ? sh.outx[e][w + 1][b] : 0.0f;
        float4 gF;
        gF.x = cc.y - cc.x;
        gF.y = cc.z - cc.y;
        gF.z = cc.w - cc.z;
        gF.w = (f0 < FF - 4) ? (nxx - cc.w) : 0.f;
        const float4 nb = nbvec(gB, gT, gF, s);
        const float4 p0 = h2f(P0[le]);
        const float4 p1 = h2f(P1[le]);
        const float4 p2 = h2f(P2[le]);
        float4 n0, n1, n2;
        n0.x = fmaf(-TAU, gB.x, p0.x) * nb.x;
        n0.y = fmaf(-TAU, gB.y, p0.y) * nb.y;
        n0.z = fmaf(-TAU, gB.z, p0.z) * nb.z;
        n0.w = fmaf(-TAU, gB.w, p0.w) * nb.w;
        n1.x = fmaf(-TAU, gT.x, p1.x) * nb.x;
        n1.y = fmaf(-TAU, gT.y, p1.y) * nb.y;
        n1.z = fmaf(-TAU, gT.z, p1.z) * nb.z;
        n1.w = fmaf(-TAU, gT.w, p1.w) * nb.w;
        n2.x = fmaf(-TAU, gF.x, p2.x) * nb.x;
        n2.y = fmaf(-TAU, gF.y, p2.y) * nb.y;
        n2.z = fmaf(-TAU, gF.z, p2.z) * nb.z;
        n2.w = fmaf(-TAU, gF.w, p2.w) * nb.w;
        P0[le] = f2h(n0);
        P1[le] = f2h(n1);
        P2[le] = f2h(n2);
    }
}

template<bool ELO, bool EHI>
__device__ __forceinline__ void tail_main(
    const float* __restrict__ x, const __half* __restrict__ pin,
    const float* __restrict__ bias, float* __restrict__ out,
    ConeSharedT& sh, int rg, int c, int b, int fg, int w, int f0, int tb, int e0,
    int base, float s) {
    h4 P0[GRT], P1[GRT], P2[GRT];
    float4 O[GRT], Xr[GRT];
    #pragma unroll
    for (int le = 0; le < GRT; ++le) {
        const int t = tb + e0 + le;
        const bool ok = (!ELO || t >= 0) && (!EHI || t < TT);
        const bool trim = (rg == 0 && le == 0);          // row 0: only P1 ever read
        if (ok) {
            const int v = base + t * ST;
            P1[le] = ld4hp(pin + NV + v);
            if (!trim) {
                P0[le] = ld4hp(pin + v);
                P2[le] = ld4hp(pin + 2 * NV + v);
                Xr[le] = ld4(x + v);
            } else { P0[le] = h4z(); P2[le] = h4z(); Xr[le] = f4z(); }
        } else {
            P0[le] = h4z(); P1[le] = h4z(); P2[le] = h4z(); Xr[le] = f4z();
        }
        O[le] = f4z();
    }
    // 4 cone iterations (iters 26..29)
    #pragma unroll
    for (int k = 0; k < 4; ++k) {
        if (rg == 0) publish_t<0>(k, P1, P2, sh, c, b, fg, w);
        else         publish_t<1>(k, P1, P2, sh, c, b, fg, w);
        __syncthreads();
        if (rg == 0) phase_out_t<0, ELO, EHI>(k, Xr, P0, P1, P2, O, sh, c, b, fg, w, f0, tb);
        else         phase_out_t<1, ELO, EHI>(k, Xr, P0, P1, P2, O, sh, c, b, fg, w, f0, tb);
        if (rg == 1) sh.oif[c] = O[0];
        __syncthreads();
        if (rg == 0) phase_upd_t<0, ELO, EHI>(k, P0, P1, P2, O, sh, c, b, fg, w, f0, tb, s);
        else         phase_upd_t<1, ELO, EHI>(k, P0, P1, P2, O, sh, c, b, fg, w, f0, tb, s);
    }
    // final div with 29-update p: publish(k=4) -> barrier -> phase_out(k=4).
    // No barrier needed before publish_t(4): its p1if/p2b writes vs
    // phase_out(3)'s reads are ordered by iter-3's second sync; upd(3)'s outx
    // reads vs phase_out(4)'s writes are ordered by the sync below.
    if (rg == 0) publish_t<0>(4, P1, P2, sh, c, b, fg, w);
    else         publish_t<1>(4, P1, P2, sh, c, b, fg, w);
    __syncthreads();
    if (rg == 0) phase_out_t<0, ELO, EHI>(4, Xr, P0, P1, P2, O, sh, c, b, fg, w, f0, tb);
    else         phase_out_t<1, ELO, EHI>(4, Xr, P0, P1, P2, O, sh, c, b, fg, w, f0, tb);
    const float4 bi = ld4(bias + f0);
    #pragma unroll
    for (int le = 0; le < GRT; ++le) {
        const int e = e0 + le;
        if (e >= HLT && e < HLT + RR) {                  // owned rows rel [5,13)
            const int t = tb + e;
            const float4 o = O[le];
            st4(out + base + t * ST,
                make_float4(o.x + bi.x, o.y + bi.y, o.z + bi.z, o.w + bi.w));
        }
    }
}

__global__ __launch_bounds__(512, 2)
void k_tail(const float* __restrict__ x, const __half* __restrict__ pin,
            const float* __restrict__ lam, const float* __restrict__ bias,
            float* __restrict__ out) {
    __shared__ ConeSharedT sh;
    const int tid = threadIdx.x;
    const int blk = blockIdx.x;
    const int rg  = tid >> 8;
    const int c   = tid & 255;
    const int b   = tid & 7;
    const int fg  = (tid >> 3) & 7;
    const int w   = (tid >> 6) & 3;
    const int f0  = w * 32 + fg * 4;
    const int tb  = blk * RR - HLT;
    const int e0  = rg * GRT;
    const int base = b * SB + f0;
    const float s = TAU / lam[0];
    if (blk == 0 || blk == NBLK - 1)
        tail_main<true, true>(x, pin, bias, out, sh, rg, c, b, fg, w, f0, tb, e0, base, s);
    else
        tail_main<false, false>(x, pin, bias, out, sh, rg, c, b, fg, w, f0, tb, e0, base, s);
}

extern "C" void kernel_launch(void* const* d_in, const int* in_sizes, int n_in,
                              void* d_out, int out_size, void* d_ws, size_t ws_size,
                              hipStream_t stream) {
    const float* x    = (const float*)d_in[0];
    const float* lam  = (const float*)d_in[1];
    const float* bias = (const float*)d_in[2];
    float* out = (float*)d_out;

    __half* pA = (__half*)d_ws;                   // 3*NV halfs = 12.6 MB
    __half* pB = pA + 3 * NV;

    // iterations 1..5 (iter-1 specialization + 4 cone iters)
    k_first<<<NBLK, 512, 0, stream>>>(x, pA, lam);
    // iterations 6..25: 5 launches x 4
    __half* pin = pA;
    __half* pout = pB;
    for (int i = 0; i < 5; ++i) {
        k_mid<<<NBLK, 512, 0, stream>>>(x, pin, pout, lam);
        __half* tmp = pin; pin = pout; pout = tmp;
    }
    // iterations 26..29 + fused out = x + div(p) + bias
    k_tail<<<NBLK, 512, 0, stream>>>(x, pin, lam, bias, out);
}

// Round 11
// 245.837 us; speedup vs baseline: 1.0049x; 1.0049x over previous
//
#include <hip/hip_runtime.h>
#include <hip/hip_fp16.h>

// TV Chambolle, image (8, 2048, 128) f32: 29 p-updates + final out = x + div(p) + bias.
// v = b*SB + t*ST + f.
//
// FINAL (R23 = R21, session best 245.4us): R13 fp32 cone kernels + packed-P
// fused tail. 7 dispatches: k_first (iter 1 + 4 cone) + 5 x k_mid (4 cone) +
// k_tail (4 cone + fused div+bias).
//
// Session summary (R12 255.9 -> 245.4):
//  - WIN: DPP row_shr/row_shl for all distance-1 b-direction lane moves
//    (VALU, off the DS pipe); distance-8 f-moves stay __shfl (DPP cannot
//    cross 16-lane rows; boundary consumers not all masked).
//  - WIN (structural, neutral time but -1 dispatch): div+bias fused into the
//    last cone launch via packed-fp16 P registers (EET=18, GR=9 fits ~155
//    regs where fp32 GR=9 spilled at ~205).
//  - NULL (measured exhaustively): occupancy >2 waves/SIMD -- this toolchain
//    pins the VGPR cap to 64 for every 4-waves/EU request ((512,4), (1024,*),
//    amdgpu_waves_per_eu(4)) causing catastrophic scratch spill; (512,2) is
//    the only sane bound. Persistent cooperative kernel 3.7x worse (spill in
//    hot loop at the 128 cap). HH=4 optimal. Packing cone kernels costs more
//    in cvt than it gains. 2 barriers/iter semantically forced by cross-wave
//    t-direction LDS exchange (outx/oif + p2b/p1if), any layout.
// Floor: ~7 launches x (~7us fixed + ~9us VALU + ~5us mem + barrier/stall) at
// toolchain-capped 2 waves/SIMD. VALUBusy ~25%, HBM ~15% -- latency-bound.

#define BB 8
#define TT 2048
#define FF 128
#define NV (BB*TT*FF)        // 2,097,152
#define SB (TT*FF)           // 262144
#define ST FF                // 128
#define RR 8                 // owned t-rows per block
#define NBLK (TT/RR)         // 256
#define HH 4                 // cone iterations per launch
#define EE 16                // extended rows (k_first / k_mid)
#define GR 8                 // rows per row-group (k_first / k_mid)
#define EET 18               // extended rows (k_tail)
#define GRT 9                // rows per row-group (k_tail)
#define HLT 5                // tail halo below owned

constexpr float TAU = 1.0f / 6.0f;

__device__ __forceinline__ float4 ld4(const float* p) { return *reinterpret_cast<const float4*>(p); }
__device__ __forceinline__ void st4(float* p, const float4& v) { *reinterpret_cast<float4*>(p) = v; }
// packed fp16 <-> fp32x4 (8-byte transactions)
__device__ __forceinline__ float4 ld4h(const __half* p) {
    uint2 u = *reinterpret_cast<const uint2*>(p);
    __half2 h0 = *reinterpret_cast<__half2*>(&u.x);
    __half2 h1 = *reinterpret_cast<__half2*>(&u.y);
    float2 a = __half22float2(h0), b2 = __half22float2(h1);
    return make_float4(a.x, a.y, b2.x, b2.y);
}
__device__ __forceinline__ void st4h(__half* p, const float4& v) {
    __half2 h0 = __float22half2_rn(make_float2(v.x, v.y));
    __half2 h1 = __float22half2_rn(make_float2(v.z, v.w));
    uint2 u;
    u.x = *reinterpret_cast<unsigned*>(&h0);
    u.y = *reinterpret_cast<unsigned*>(&h1);
    *reinterpret_cast<uint2*>(p) = u;
}
// packed 4 x fp16 in registers (2 VGPRs) -- tail only
struct h4 { __half2 lo, hi; };
__device__ __forceinline__ float4 h2f(const h4& h) {
    float2 a = __half22float2(h.lo), b = __half22float2(h.hi);
    return make_float4(a.x, a.y, b.x, b.y);
}
__device__ __forceinline__ h4 f2h(const float4& v) {
    h4 r;
    r.lo = __float22half2_rn(make_float2(v.x, v.y));
    r.hi = __float22half2_rn(make_float2(v.z, v.w));
    return r;
}
__device__ __forceinline__ h4 h4z() {
    h4 r; unsigned z = 0;
    r.lo = *reinterpret_cast<__half2*>(&z);
    r.hi = *reinterpret_cast<__half2*>(&z);
    return r;
}
__device__ __forceinline__ h4 ld4hp(const __half* p) {   // raw 8B, no cvt
    uint2 u = *reinterpret_cast<const uint2*>(p);
    h4 r;
    r.lo = *reinterpret_cast<__half2*>(&u.x);
    r.hi = *reinterpret_cast<__half2*>(&u.y);
    return r;
}

// DPP lane shifts (VALU, no DS pipe). row_shr:1 = src[n-1] (shfl_up 1);
// row_shl:1 = src[n+1] (shfl_down 1). 16-lane-row boundary lanes -> 0
// (bound_ctrl=1); all consumers masked by b>0 / b<BB-1 which covers them.
__device__ __forceinline__ float dpp_shr1(float v) {
    return __int_as_float(__builtin_amdgcn_update_dpp(
        0, __float_as_int(v), 0x111, 0xF, 0xF, true));
}
__device__ __forceinline__ float dpp_shl1(float v) {
    return __int_as_float(__builtin_amdgcn_update_dpp(
        0, __float_as_int(v), 0x101, 0xF, 0xF, true));
}
__device__ __forceinline__ float4 dpp_up4(const float4& v) {
    return make_float4(dpp_shr1(v.x), dpp_shr1(v.y), dpp_shr1(v.z), dpp_shr1(v.w));
}
__device__ __forceinline__ float4 dpp_dn4(const float4& v) {
    return make_float4(dpp_shl1(v.x), dpp_shl1(v.y), dpp_shl1(v.z), dpp_shl1(v.w));
}
__device__ __forceinline__ h4 dpp_up_h4(const h4& v) {   // packed: 2 DPP ops
    unsigned lo = *reinterpret_cast<const unsigned*>(&v.lo);
    unsigned hi = *reinterpret_cast<const unsigned*>(&v.hi);
    unsigned rl = (unsigned)__builtin_amdgcn_update_dpp(0, (int)lo, 0x111, 0xF, 0xF, true);
    unsigned rh = (unsigned)__builtin_amdgcn_update_dpp(0, (int)hi, 0x111, 0xF, 0xF, true);
    h4 r;
    r.lo = *reinterpret_cast<__half2*>(&rl);
    r.hi = *reinterpret_cast<__half2*>(&rh);
    return r;
}
__device__ __forceinline__ float4 sub4(const float4& a, const float4& b) {
    return make_float4(a.x - b.x, a.y - b.y, a.z - b.z, a.w - b.w);
}
__device__ __forceinline__ float4 f4z() { return make_float4(0.f, 0.f, 0.f, 0.f); }
// 1/(|g|*s + 1) elementwise; v_sqrt_f32 + v_rcp_f32 approx.
__device__ __forceinline__ float4 nbvec(const float4& gB, const float4& gT, const float4& gF, float s) {
    float4 nb; float q;
    q = gB.x * gB.x + gT.x * gT.x + gF.x * gF.x;
    nb.x = __builtin_amdgcn_rcpf(fmaf(__builtin_amdgcn_sqrtf(q), s, 1.f));
    q = gB.y * gB.y + gT.y * gT.y + gF.y * gF.y;
    nb.y = __builtin_amdgcn_rcpf(fmaf(__builtin_amdgcn_sqrtf(q), s, 1.f));
    q = gB.z * gB.z + gT.z * gT.z + gF.z * gF.z;
    nb.z = __builtin_amdgcn_rcpf(fmaf(__builtin_amdgcn_sqrtf(q), s, 1.f));
    q = gB.w * gB.w + gT.w * gT.w + gF.w * gF.w;
    nb.w = __builtin_amdgcn_rcpf(fmaf(__builtin_amdgcn_sqrtf(q), s, 1.f));
    return nb;
}

// ==================================================================
// ============== fp32 cone (k_first / k_mid) -- R13 =================
// ==================================================================
struct ConeShared {                      // ~10 KB
    float p2b[EE][4][8];
    float outx[EE][4][8];
    float4 p1if[256];
    float4 oif[256];
};

template<int RG>
__device__ __forceinline__ void publish(int k, float4 (&P1)[GR], float4 (&P2)[GR],
                                        ConeShared& sh, int c, int b, int fg, int w) {
    if (fg == 7) {
        #pragma unroll
        for (int le = 0; le < GR; ++le) {
            const int e = RG * GR + le;
            if (e >= k && e < EE - k) sh.p2b[e][w][b] = P2[le].w;
        }
    }
    if (RG == 0) sh.p1if[c] = P1[GR - 1];
}

template<int RG, bool ELO, bool EHI>
__device__ __forceinline__ void phase_out(
    int k, const float4 (&Xr)[GR],
    float4 (&P0)[GR], float4 (&P1)[GR], float4 (&P2)[GR], float4 (&O)[GR],
    ConeShared& sh, int c, int b, int fg, int w, int f0, int tb) {
    #pragma unroll
    for (int le = 0; le < GR; ++le) {
        const int e = RG * GR + le;
        if (e < k + 1 || e >= EE - k) continue;
        const int t = tb + e;
        if ((ELO && t < 0) || (EHI && t >= TT)) continue;
        const float4 X = Xr[le];
        float4 o;
        o.x = X.x - P0[le].x - P1[le].x - P2[le].x;
        o.y = X.y - P0[le].y - P1[le].y - P2[le].y + P2[le].x;
        o.z = X.z - P0[le].z - P1[le].z - P2[le].z + P2[le].y;
        o.w = X.w - P0[le].w - P1[le].w - P2[le].w + P2[le].z;
        float4 h0 = dpp_up4(P0[le]);
        if (b > 0) { o.x += h0.x; o.y += h0.y; o.z += h0.z; o.w += h0.w; }
        float4 pm1 = (le > 0) ? P1[le - 1] : sh.p1if[c];
        if (!ELO || t > 0) { o.x += pm1.x; o.y += pm1.y; o.z += pm1.z; o.w += pm1.w; }
        float pw = __shfl_up(P2[le].w, 8);
        if (fg == 0) pw = (w > 0) ? sh.p2b[e][(w - 1)][b] : 0.0f;
        if (f0 > 0) o.x += pw;
        O[le] = o;
        if (fg == 0) sh.outx[e][w][b] = o.x;
    }
}

template<int RG, bool ELO, bool EHI>
__device__ __forceinline__ void phase_upd(
    int k, float4 (&P0)[GR], float4 (&P1)[GR], float4 (&P2)[GR], float4 (&O)[GR],
    ConeShared& sh, int c, int b, int fg, int w, int f0, int tb, float s) {
    #pragma unroll
    for (int le = 0; le < GR; ++le) {
        const int e = RG * GR + le;
        if (e < k + 1 || e > EE - 2 - k) continue;
        const int t = tb + e;
        if ((ELO && t < 0) || (EHI && t >= TT)) continue;
        const float4 cc = O[le];
        const float4 on = (le < GR - 1) ? O[le + 1] : sh.oif[c];
        float4 gT = f4z();
        if (!EHI || t < TT - 1) gT = sub4(on, cc);
        const float4 nB = dpp_dn4(cc);
        float4 gB = f4z();
        if (b < BB - 1) gB = sub4(nB, cc);
        float nxx = __shfl_down(cc.x, 8);
        if (fg == 7) nxx = (w < 3) ? sh.outx[e][w + 1][b] : 0.0f;
        float4 gF;
        gF.x = cc.y - cc.x;
        gF.y = cc.z - cc.y;
        gF.z = cc.w - cc.z;
        gF.w = (f0 < FF - 4) ? (nxx - cc.w) : 0.f;
        const float4 nb = nbvec(gB, gT, gF, s);
        P0[le].x = fmaf(-TAU, gB.x, P0[le].x) * nb.x;
        P0[le].y = fmaf(-TAU, gB.y, P0[le].y) * nb.y;
        P0[le].z = fmaf(-TAU, gB.z, P0[le].z) * nb.z;
        P0[le].w = fmaf(-TAU, gB.w, P0[le].w) * nb.w;
        P1[le].x = fmaf(-TAU, gT.x, P1[le].x) * nb.x;
        P1[le].y = fmaf(-TAU, gT.y, P1[le].y) * nb.y;
        P1[le].z = fmaf(-TAU, gT.z, P1[le].z) * nb.z;
        P1[le].w = fmaf(-TAU, gT.w, P1[le].w) * nb.w;
        P2[le].x = fmaf(-TAU, gF.x, P2[le].x) * nb.x;
        P2[le].y = fmaf(-TAU, gF.y, P2[le].y) * nb.y;
        P2[le].z = fmaf(-TAU, gF.z, P2[le].z) * nb.z;
        P2[le].w = fmaf(-TAU, gF.w, P2[le].w) * nb.w;
    }
}

template<bool ELO, bool EHI>
__device__ __forceinline__ void cone_run(
    const float4 (&Xr)[GR],
    float4 (&P0)[GR], float4 (&P1)[GR], float4 (&P2)[GR], float4 (&O)[GR],
    ConeShared& sh, int rg, int c, int b, int fg, int w, int f0, int tb, float s) {
    #pragma unroll
    for (int k = 0; k < HH; ++k) {
        if (rg == 0) publish<0>(k, P1, P2, sh, c, b, fg, w);
        else         publish<1>(k, P1, P2, sh, c, b, fg, w);
        __syncthreads();
        if (rg == 0) phase_out<0, ELO, EHI>(k, Xr, P0, P1, P2, O, sh, c, b, fg, w, f0, tb);
        else         phase_out<1, ELO, EHI>(k, Xr, P0, P1, P2, O, sh, c, b, fg, w, f0, tb);
        if (rg == 1) sh.oif[c] = O[0];
        __syncthreads();
        if (rg == 0) phase_upd<0, ELO, EHI>(k, P0, P1, P2, O, sh, c, b, fg, w, f0, tb, s);
        else         phase_upd<1, ELO, EHI>(k, P0, P1, P2, O, sh, c, b, fg, w, f0, tb, s);
    }
}

template<bool ELO, bool EHI>
__device__ __forceinline__ void mid_main(
    const float* __restrict__ x, const __half* __restrict__ pin, __half* __restrict__ pout,
    ConeShared& sh, int rg, int c, int b, int fg, int w, int f0, int tb, int e0,
    int base, float s) {
    float4 P0[GR], P1[GR], P2[GR], O[GR], Xr[GR];
    #pragma unroll
    for (int le = 0; le < GR; ++le) {
        const int t = tb + e0 + le;
        const bool ok = (!ELO || t >= 0) && (!EHI || t < TT);
        const bool trim = (rg == 0 && le == 0);
        if (ok) {
            const int v = base + t * ST;
            P1[le] = ld4h(pin + NV + v);
            if (!trim) {
                P0[le] = ld4h(pin + v);
                P2[le] = ld4h(pin + 2 * NV + v);
                Xr[le] = ld4(x + v);
            } else { P0[le] = f4z(); P2[le] = f4z(); Xr[le] = f4z(); }
        } else {
            P0[le] = f4z(); P1[le] = f4z(); P2[le] = f4z(); Xr[le] = f4z();
        }
        O[le] = f4z();
    }
    cone_run<ELO, EHI>(Xr, P0, P1, P2, O, sh, rg, c, b, fg, w, f0, tb, s);
    #pragma unroll
    for (int le = 0; le < GR; ++le) {
        const int e = e0 + le;
        if (e >= HH && e < HH + RR) {
            const int v = base + (tb + e) * ST;
            st4h(pout + v, P0[le]);
            st4h(pout + NV + v, P1[le]);
            st4h(pout + 2 * NV + v, P2[le]);
        }
    }
}

__global__ __launch_bounds__(512, 2)
void k_mid(const float* __restrict__ x, const __half* __restrict__ pin,
           __half* __restrict__ pout, const float* __restrict__ lam) {
    __shared__ ConeShared sh;
    const int tid = threadIdx.x;
    const int blk = blockIdx.x;
    const int rg  = tid >> 8;
    const int c   = tid & 255;
    const int b   = tid & 7;
    const int fg  = (tid >> 3) & 7;
    const int w   = (tid >> 6) & 3;
    const int f0  = w * 32 + fg * 4;
    const int tb  = blk * RR - HH;
    const int e0  = rg * GR;
    const int base = b * SB + f0;
    const float s = TAU / lam[0];
    if (blk == 0 || blk == NBLK - 1)
        mid_main<true, true>(x, pin, pout, sh, rg, c, b, fg, w, f0, tb, e0, base, s);
    else
        mid_main<false, false>(x, pin, pout, sh, rg, c, b, fg, w, f0, tb, e0, base, s);
}

template<bool ELO, bool EHI>
__device__ __forceinline__ void first_main(
    const float* __restrict__ x, __half* __restrict__ pout,
    ConeShared& sh, int rg, int c, int b, int fg, int w, int f0, int tb, int e0,
    int base, float s) {
    float4 P0[GR], P1[GR], P2[GR], O[GR], Xr[GR], XHa;
    #pragma unroll
    for (int le = 0; le < GR; ++le) {
        const int t = tb + e0 + le;
        const bool ok = (!ELO || t >= 0) && (!EHI || t < TT);
        Xr[le] = ok ? ld4(x + base + t * ST) : f4z();
        O[le] = f4z();
    }
    {
        const int t = tb + e0 + GR;
        const bool ok = (!ELO || t >= 0) && (t < TT);
        XHa = ok ? ld4(x + base + t * ST) : f4z();
    }
    #pragma unroll
    for (int le = 0; le < GR; ++le) {
        const int t = tb + e0 + le;
        if ((!ELO || t >= 0) && (!EHI || t < TT)) {
            const float4 cc = Xr[le];
            const float4 nxt = (le < GR - 1) ? Xr[le + 1] : XHa;
            float4 gT = f4z();
            if (t < TT - 1) gT = sub4(nxt, cc);
            const float4 nB = dpp_dn4(cc);
            float4 gB = f4z();
            if (b < BB - 1) gB = sub4(nB, cc);
            float4 gF;
            gF.x = cc.y - cc.x;
            gF.y = cc.z - cc.y;
            gF.z = cc.w - cc.z;
            gF.w = (f0 < FF - 4) ? (x[base + t * ST + 4] - cc.w) : 0.f;
            const float4 nb = nbvec(gB, gT, gF, s);
            P0[le] = make_float4(-TAU * gB.x * nb.x, -TAU * gB.y * nb.y,
                                 -TAU * gB.z * nb.z, -TAU * gB.w * nb.w);
            P1[le] = make_float4(-TAU * gT.x * nb.x, -TAU * gT.y * nb.y,
                                 -TAU * gT.z * nb.z, -TAU * gT.w * nb.w);
            P2[le] = make_float4(-TAU * gF.x * nb.x, -TAU * gF.y * nb.y,
                                 -TAU * gF.z * nb.z, -TAU * gF.w * nb.w);
        } else {
            P0[le] = f4z(); P1[le] = f4z(); P2[le] = f4z();
        }
    }
    cone_run<ELO, EHI>(Xr, P0, P1, P2, O, sh, rg, c, b, fg, w, f0, tb, s);
    #pragma unroll
    for (int le = 0; le < GR; ++le) {
        const int e = e0 + le;
        if (e >= HH && e < HH + RR) {
            const int v = base + (tb + e) * ST;
            st4h(pout + v, P0[le]);
            st4h(pout + NV + v, P1[le]);
            st4h(pout + 2 * NV + v, P2[le]);
        }
    }
}

__global__ __launch_bounds__(512, 2)
void k_first(const float* __restrict__ x, __half* __restrict__ pout,
             const float* __restrict__ lam) {
    __shared__ ConeShared sh;
    const int tid = threadIdx.x;
    const int blk = blockIdx.x;
    const int rg  = tid >> 8;
    const int c   = tid & 255;
    const int b   = tid & 7;
    const int fg  = (tid >> 3) & 7;
    const int w   = (tid >> 6) & 3;
    const int f0  = w * 32 + fg * 4;
    const int tb  = blk * RR - HH;
    const int e0  = rg * GR;
    const int base = b * SB + f0;
    const float s = TAU / lam[0];
    if (blk == 0 || blk == NBLK - 1)
        first_main<true, true>(x, pout, sh, rg, c, b, fg, w, f0, tb, e0, base, s);
    else
        first_main<false, false>(x, pout, sh, rg, c, b, fg, w, f0, tb, e0, base, s);
}

// ==================================================================
// ============== packed-P cone tail (EE=18, GR=9) ===================
// ==================================================================
struct ConeSharedT {                     // ~10.8 KB
    float p2b[EET][4][8];
    float outx[EET][4][8];
    h4 p1if[256];
    float4 oif[256];
};

template<int RG>
__device__ __forceinline__ void publish_t(int k, h4 (&P1)[GRT], h4 (&P2)[GRT],
                                          ConeSharedT& sh, int c, int b, int fg, int w) {
    if (fg == 7) {
        #pragma unroll
        for (int le = 0; le < GRT; ++le) {
            const int e = RG * GRT + le;
            if (e >= k && e < EET - k) sh.p2b[e][w][b] = __high2float(P2[le].hi);
        }
    }
    if (RG == 0) sh.p1if[c] = P1[GRT - 1];
}

template<int RG, bool ELO, bool EHI>
__device__ __forceinline__ void phase_out_t(
    int k, const float4 (&Xr)[GRT],
    h4 (&P0)[GRT], h4 (&P1)[GRT], h4 (&P2)[GRT], float4 (&O)[GRT],
    ConeSharedT& sh, int c, int b, int fg, int w, int f0, int tb) {
    #pragma unroll
    for (int le = 0; le < GRT; ++le) {
        const int e = RG * GRT + le;
        if (e < k + 1 || e >= EET - k) continue;
        const int t = tb + e;
        if ((ELO && t < 0) || (EHI && t >= TT)) continue;
        const float4 X = Xr[le];
        const float4 p0 = h2f(P0[le]);
        const float4 p1 = h2f(P1[le]);
        const float4 p2 = h2f(P2[le]);
        float4 o;
        o.x = X.x - p0.x - p1.x - p2.x;
        o.y = X.y - p0.y - p1.y - p2.y + p2.x;
        o.z = X.z - p0.z - p1.z - p2.z + p2.y;
        o.w = X.w - p0.w - p1.w - p2.w + p2.z;
        const float4 h0 = h2f(dpp_up_h4(P0[le]));
        if (b > 0) { o.x += h0.x; o.y += h0.y; o.z += h0.z; o.w += h0.w; }
        const h4 pm1h = (le > 0) ? P1[le - 1] : sh.p1if[c];
        const float4 pm1 = h2f(pm1h);
        if (!ELO || t > 0) { o.x += pm1.x; o.y += pm1.y; o.z += pm1.z; o.w += pm1.w; }
        float pw = __shfl_up(p2.w, 8);
        if (fg == 0) pw = (w > 0) ? sh.p2b[e][(w - 1)][b] : 0.0f;
        if (f0 > 0) o.x += pw;
        O[le] = o;
        if (fg == 0) sh.outx[e][w][b] = o.x;
    }
}

template<int RG, bool ELO, bool EHI>
__device__ __forceinline__ void phase_upd_t(
    int k, h4 (&P0)[GRT], h4 (&P1)[GRT], h4 (&P2)[GRT], float4 (&O)[GRT],
    ConeSharedT& sh, int c, int b, int fg, int w, int f0, int tb, float s) {
    #pragma unroll
    for (int le = 0; le < GRT; ++le) {
        const int e = RG * GRT + le;
        if (e < k + 1 || e > EET - 2 - k) continue;
        const int t = tb + e;
        if ((ELO && t < 0) || (EHI && t >= TT)) continue;
        const float4 cc = O[le];
        const float4 on = (le < GRT - 1) ? O[le + 1] : sh.oif[c];
        float4 gT = f4z();
        if (!EHI || t < TT - 1) gT = sub4(on, cc);
        const float4 nB = dpp_dn4(cc);
        float4 gB = f4z();
        if (b < BB - 1) gB = sub4(nB, cc);
        float nxx = __shfl_down(cc.x, 8);
        if (fg == 7) nxx = (w < 3) ? sh.outx[e][w + 1][b] : 0.0f;
        float4 gF;
        gF.x = cc.y - cc.x;
        gF.y = cc.z - cc.y;
        gF.z = cc.w - cc.z;
        gF.w = (f0 < FF - 4) ? (nxx - cc.w) : 0.f;
        const float4 nb = nbvec(gB, gT, gF, s);
        const float4 p0 = h2f(P0[le]);
        const float4 p1 = h2f(P1[le]);
        const float4 p2 = h2f(P2[le]);
        float4 n0, n1, n2;
        n0.x = fmaf(-TAU, gB.x, p0.x) * nb.x;
        n0.y = fmaf(-TAU, gB.y, p0.y) * nb.y;
        n0.z = fmaf(-TAU, gB.z, p0.z) * nb.z;
        n0.w = fmaf(-TAU, gB.w, p0.w) * nb.w;
        n1.x = fmaf(-TAU, gT.x, p1.x) * nb.x;
        n1.y = fmaf(-TAU, gT.y, p1.y) * nb.y;
        n1.z = fmaf(-TAU, gT.z, p1.z) * nb.z;
        n1.w = fmaf(-TAU, gT.w, p1.w) * nb.w;
        n2.x = fmaf(-TAU, gF.x, p2.x) * nb.x;
        n2.y = fmaf(-TAU, gF.y, p2.y) * nb.y;
        n2.z = fmaf(-TAU, gF.z, p2.z) * nb.z;
        n2.w = fmaf(-TAU, gF.w, p2.w) * nb.w;
        P0[le] = f2h(n0);
        P1[le] = f2h(n1);
        P2[le] = f2h(n2);
    }
}

template<bool ELO, bool EHI>
__device__ __forceinline__ void tail_main(
    const float* __restrict__ x, const __half* __restrict__ pin,
    const float* __restrict__ bias, float* __restrict__ out,
    ConeSharedT& sh, int rg, int c, int b, int fg, int w, int f0, int tb, int e0,
    int base, float s) {
    h4 P0[GRT], P1[GRT], P2[GRT];
    float4 O[GRT], Xr[GRT];
    #pragma unroll
    for (int le = 0; le < GRT; ++le) {
        const int t = tb + e0 + le;
        const bool ok = (!ELO || t >= 0) && (!EHI || t < TT);
        const bool trim = (rg == 0 && le == 0);          // row 0: only P1 ever read
        if (ok) {
            const int v = base + t * ST;
            P1[le] = ld4hp(pin + NV + v);
            if (!trim) {
                P0[le] = ld4hp(pin + v);
                P2[le] = ld4hp(pin + 2 * NV + v);
                Xr[le] = ld4(x + v);
            } else { P0[le] = h4z(); P2[le] = h4z(); Xr[le] = f4z(); }
        } else {
            P0[le] = h4z(); P1[le] = h4z(); P2[le] = h4z(); Xr[le] = f4z();
        }
        O[le] = f4z();
    }
    // 4 cone iterations (iters 26..29)
    #pragma unroll
    for (int k = 0; k < 4; ++k) {
        if (rg == 0) publish_t<0>(k, P1, P2, sh, c, b, fg, w);
        else         publish_t<1>(k, P1, P2, sh, c, b, fg, w);
        __syncthreads();
        if (rg == 0) phase_out_t<0, ELO, EHI>(k, Xr, P0, P1, P2, O, sh, c, b, fg, w, f0, tb);
        else         phase_out_t<1, ELO, EHI>(k, Xr, P0, P1, P2, O, sh, c, b, fg, w, f0, tb);
        if (rg == 1) sh.oif[c] = O[0];
        __syncthreads();
        if (rg == 0) phase_upd_t<0, ELO, EHI>(k, P0, P1, P2, O, sh, c, b, fg, w, f0, tb, s);
        else         phase_upd_t<1, ELO, EHI>(k, P0, P1, P2, O, sh, c, b, fg, w, f0, tb, s);
    }
    // final div with 29-update p: publish(k=4) -> barrier -> phase_out(k=4)
    __syncthreads();
    if (rg == 0) publish_t<0>(4, P1, P2, sh, c, b, fg, w);
    else         publish_t<1>(4, P1, P2, sh, c, b, fg, w);
    __syncthreads();
    if (rg == 0) phase_out_t<0, ELO, EHI>(4, Xr, P0, P1, P2, O, sh, c, b, fg, w, f0, tb);
    else         phase_out_t<1, ELO, EHI>(4, Xr, P0, P1, P2, O, sh, c, b, fg, w, f0, tb);
    const float4 bi = ld4(bias + f0);
    #pragma unroll
    for (int le = 0; le < GRT; ++le) {
        const int e = e0 + le;
        if (e >= HLT && e < HLT + RR) {                  // owned rows rel [5,13)
            const int t = tb + e;
            const float4 o = O[le];
            st4(out + base + t * ST,
                make_float4(o.x + bi.x, o.y + bi.y, o.z + bi.z, o.w + bi.w));
        }
    }
}

__global__ __launch_bounds__(512, 2)
void k_tail(const float* __restrict__ x, const __half* __restrict__ pin,
            const float* __restrict__ lam, const float* __restrict__ bias,
            float* __restrict__ out) {
    __shared__ ConeSharedT sh;
    const int tid = threadIdx.x;
    const int blk = blockIdx.x;
    const int rg  = tid >> 8;
    const int c   = tid & 255;
    const int b   = tid & 7;
    const int fg  = (tid >> 3) & 7;
    const int w   = (tid >> 6) & 3;
    const int f0  = w * 32 + fg * 4;
    const int tb  = blk * RR - HLT;
    const int e0  = rg * GRT;
    const int base = b * SB + f0;
    const float s = TAU / lam[0];
    if (blk == 0 || blk == NBLK - 1)
        tail_main<true, true>(x, pin, bias, out, sh, rg, c, b, fg, w, f0, tb, e0, base, s);
    else
        tail_main<false, false>(x, pin, bias, out, sh, rg, c, b, fg, w, f0, tb, e0, base, s);
}

extern "C" void kernel_launch(void* const* d_in, const int* in_sizes, int n_in,
                              void* d_out, int out_size, void* d_ws, size_t ws_size,
                              hipStream_t stream) {
    const float* x    = (const float*)d_in[0];
    const float* lam  = (const float*)d_in[1];
    const float* bias = (const float*)d_in[2];
    float* out = (float*)d_out;

    __half* pA = (__half*)d_ws;                   // 3*NV halfs = 12.6 MB
    __half* pB = pA + 3 * NV;

    // iterations 1..5 (iter-1 specialization + 4 cone iters)
    k_first<<<NBLK, 512, 0, stream>>>(x, pA, lam);
    // iterations 6..25: 5 launches x 4
    __half* pin = pA;
    __half* pout = pB;
    for (int i = 0; i < 5; ++i) {
        k_mid<<<NBLK, 512, 0, stream>>>(x, pin, pout, lam);
        __half* tmp = pin; pin = pout; pout = tmp;
    }
    // iterations 26..29 + fused out = x + div(p) + bias
    k_tail<<<NBLK, 512, 0, stream>>>(x, pin, lam, bias, out);
}